// Round 12
// baseline (48.242 us; speedup 1.0000x reference)
//
#include <hip/hip_runtime.h>
#include <hip/hip_fp16.h>

#define B_  8
#define N_  100
#define T_  16
#define TP_ 15     // T-1 output steps (pred_steps == 1)
#define D_  4
#define H_  64
#define E_  9900   // N*(N-1)
#define NG  13     // 8 receivers per block (2 per wave), last group partial
#define ROWS 12000 // B*TP*N

// ---- d_ws layout (bytes) ----
#define WS_AIN 0u          // f16 [12000][96]: [agg(64)|x(4)|zeros(28)]  2,304,000
#define WS_V   2304000u    // f16 [12000][64]  receiver-side pre-act     1,536,000
#define WS_RTT 3840000u    // f32 [8][100][112] SENDER-major rel_type      358,400
#define WS_UBF 4198400u    // f16 [120][100][72] sender pre-act (+pad)   1,730,560
#define WS_W2F 5928960u    // f16 8 MFMA frags of W2^T (kernel A)            8,192
#define WS_W1F 5937152u    // f16 12 MFMA frags of W1out^T (K=96 padded)    12,288
#define WS_W2B 5949440u    // f16 8 MFMA frags of W2out^T                    8,192
#define WS_W3F 5957632u    // f16 [16][16] W3out per-lane pack               2,048
                           // total 5,959,680 B

typedef __attribute__((ext_vector_type(8))) _Float16 f16x8;
typedef __attribute__((ext_vector_type(4))) float f32x4;

__device__ __forceinline__ void gload_lds16(const void* g, void* lds) {
    __builtin_amdgcn_global_load_lds(
        (const __attribute__((address_space(1))) void*)g,
        (__attribute__((address_space(3))) void*)lds, 16, 0, 0);
}

// relu(u+v) on 8 packed f16 -> 4x v_pk_add_f16 + 4x v_pk_max_f16
__device__ __forceinline__ f16x8 relu_add8(uint4 u, uint4 v) {
    const f16x8 a = __builtin_bit_cast(f16x8, u);
    const f16x8 b = __builtin_bit_cast(f16x8, v);
    const f16x8 s = a + b;
    const f16x8 z = (f16x8)(_Float16)0;
    return __builtin_elementwise_max(s, z);
}

// ==================== prep: u/v/x rows, rtt gather, weight frags ============
__global__ __launch_bounds__(256)
void nri_prep(const float* __restrict__ x, const float* __restrict__ rel,
              const float* __restrict__ w1, const float* __restrict__ b1,
              const float* __restrict__ w2, const float* __restrict__ f1w,
              const float* __restrict__ f2w, const float* __restrict__ f3w,
              __half* __restrict__ ubf, __half* __restrict__ v_h,
              float* __restrict__ rtt, __half* __restrict__ ain,
              __half* __restrict__ w2f, __half* __restrict__ w1f,
              __half* __restrict__ w2b, __half* __restrict__ w3f)
{
    const int lane = threadIdx.x & 63;
    const int wid  = blockIdx.x * 4 + (threadIdx.x >> 6);

    if (wid < ROWS) {                       // per (b,t,node) row
        const int nn = wid % N_;
        const int bt = wid / N_;
        const int t  = bt % TP_;
        const int b  = bt / TP_;
        const float4 ws4 = *(const float4*)(w1 + lane * 8);
        const float4 wr4 = *(const float4*)(w1 + lane * 8 + 4);
        const float4 xv  = *(const float4*)(x + (((size_t)b * N_ + nn) * T_ + t) * D_);
        const float u = ws4.x * xv.x + ws4.y * xv.y + ws4.z * xv.z + ws4.w * xv.w;
        const float v = wr4.x * xv.x + wr4.y * xv.y + wr4.z * xv.z + wr4.w * xv.w
                        + b1[lane];
        ubf[(size_t)bt * 7200 + nn * 72 + lane] = __float2half(u);
        v_h[(size_t)wid * 64 + lane] = __float2half(v);
        if (lane == 32) {                   // x (f16) into ain[row][64..67]
            const unsigned short h0 = __half_as_ushort(__float2half(xv.x));
            const unsigned short h1 = __half_as_ushort(__float2half(xv.y));
            const unsigned short h2 = __half_as_ushort(__float2half(xv.z));
            const unsigned short h3 = __half_as_ushort(__float2half(xv.w));
            uint2 p; p.x = (unsigned)h0 | ((unsigned)h1 << 16);
                     p.y = (unsigned)h2 | ((unsigned)h3 << 16);
            *(uint2*)(ain + (size_t)wid * 96 + 64) = p;
        } else if (lane >= 33 && lane < 40) {  // zeros ain[row][68..95]
            uint2 zz; zz.x = 0u; zz.y = 0u;
            *(uint2*)(ain + (size_t)wid * 96 + 68 + (lane - 33) * 4) = zz;
        }
    } else if (wid < ROWS + B_ * N_) {      // rtt row per (b, receiver n), SENDER-major
        const int idx = wid - ROWS;
        const int n = idx % N_;
        const int b = idx / N_;
        float* dst = rtt + (size_t)idx * 112;
        {
            const int i = lane;             // sender 0..63
            float rv = 0.f;
            if (i != n) {
                const int e = i * (N_ - 1) + (n < i ? n : n - 1);
                rv = rel[((size_t)b * E_ + e) * 2 + 1];
            }
            dst[i] = rv;
        }
        if (lane < 48) {
            const int i2 = 64 + lane;       // sender 64..111 (>=100 -> 0)
            float rv = 0.f;
            if (i2 < N_ && i2 != n) {
                const int e2 = i2 * (N_ - 1) + (n < i2 ? n : n - 1);
                rv = rel[((size_t)b * E_ + e2) * 2 + 1];
            }
            dst[i2] = rv;
        }
    } else {                                // weight-fragment packing waves
        const int fid = wid - (ROWS + B_ * N_);
        const int g16 = lane & 15, q = lane >> 4;
        unsigned short h[8];
        if (fid < 8) {                      // W2^T frags (kernel A)
            const int s = fid >> 2, nt = fid & 3;
            const int g = nt * 16 + g16;
            #pragma unroll
            for (int j = 0; j < 8; ++j)
                h[j] = __half_as_ushort(__float2half(
                    w2[(size_t)g * 64 + s * 32 + q * 8 + j]));
            uint4 pv; pv.x = h[0] | ((unsigned)h[1] << 16); pv.y = h[2] | ((unsigned)h[3] << 16);
                      pv.z = h[4] | ((unsigned)h[5] << 16); pv.w = h[6] | ((unsigned)h[7] << 16);
            *(uint4*)(w2f + fid * 512 + lane * 8) = pv;
        } else if (fid < 20) {              // W1out^T frags, K=96: [agg|x|0]
            const int f = fid - 8;
            const int s = f >> 2, nt = f & 3;
            const int g = nt * 16 + g16;
            #pragma unroll
            for (int j = 0; j < 8; ++j) {
                const int k = s * 32 + q * 8 + j;
                float v = 0.f;
                if (k < 64)       v = f1w[(size_t)g * 68 + 4 + k];
                else if (k < 68)  v = f1w[(size_t)g * 68 + (k - 64)];
                h[j] = __half_as_ushort(__float2half(v));
            }
            uint4 pv; pv.x = h[0] | ((unsigned)h[1] << 16); pv.y = h[2] | ((unsigned)h[3] << 16);
                      pv.z = h[4] | ((unsigned)h[5] << 16); pv.w = h[6] | ((unsigned)h[7] << 16);
            *(uint4*)(w1f + f * 512 + lane * 8) = pv;
        } else if (fid < 28) {              // W2out^T frags
            const int f = fid - 20;
            const int s = f >> 2, nt = f & 3;
            const int g = nt * 16 + g16;
            #pragma unroll
            for (int j = 0; j < 8; ++j)
                h[j] = __half_as_ushort(__float2half(
                    f2w[(size_t)g * 64 + s * 32 + q * 8 + j]));
            uint4 pv; pv.x = h[0] | ((unsigned)h[1] << 16); pv.y = h[2] | ((unsigned)h[3] << 16);
                      pv.z = h[4] | ((unsigned)h[5] << 16); pv.w = h[6] | ((unsigned)h[7] << 16);
            *(uint4*)(w2b + f * 512 + lane * 8) = pv;
        } else if (fid == 28) {             // W3 per-lane pack [col][nt*4+d]
            unsigned short hh[16];
            #pragma unroll
            for (int nt = 0; nt < 4; ++nt)
                #pragma unroll
                for (int d = 0; d < 4; ++d)
                    hh[nt * 4 + d] = __half_as_ushort(__float2half(
                        f3w[d * 64 + nt * 16 + g16]));
            uint4 p0, p1;
            p0.x = hh[0] | ((unsigned)hh[1] << 16);  p0.y = hh[2] | ((unsigned)hh[3] << 16);
            p0.z = hh[4] | ((unsigned)hh[5] << 16);  p0.w = hh[6] | ((unsigned)hh[7] << 16);
            p1.x = hh[8] | ((unsigned)hh[9] << 16);  p1.y = hh[10] | ((unsigned)hh[11] << 16);
            p1.z = hh[12] | ((unsigned)hh[13] << 16); p1.w = hh[14] | ((unsigned)hh[15] << 16);
            *(uint4*)(w3f + lane * 16) = p0;
            *(uint4*)(w3f + lane * 16 + 8) = p1;
        }
    }
}

// ==================== kernel A: message MLP + aggregation ===================
// 1560 blocks x 4 waves; TWO receivers per wave (n0 = g*8+w, n1 = n0+4).
// Sender-direct row indexing: u ds_reads shared by both receivers; self/pad
// edges masked by rt=0. setprio(1) around the MFMA cluster (T5).
__global__ __launch_bounds__(256)
void nri_agg(const __half* __restrict__ ubf, const __half* __restrict__ v_h,
             const float* __restrict__ rtt, const __half* __restrict__ w2f,
             const float* __restrict__ b2, __half* __restrict__ ain)
{
    __shared__ __half u_lds[7680];          // 15,360 B (100 rows x 72 + pad)

    const int tid  = threadIdx.x;
    const int lane = tid & 63;
    const int w    = tid >> 6;
    const int bid  = blockIdx.x;
    const int g  = bid % NG;
    const int t  = (bid / NG) % TP_;
    const int b  = bid / (NG * TP_);
    const int bt = b * TP_ + t;

    // u-tile DMA: 15 x 1KB chunks
    {
        const char* gsrc = (const char*)(ubf + (size_t)bt * 7200);
        char* ldst = (char*)u_lds;
        #pragma unroll
        for (int j = 0; j < 4; ++j) {
            const int c = w + 4 * j;        // wave-uniform
            if (c < 15)
                gload_lds16(gsrc + c * 1024 + lane * 16, ldst + c * 1024);
        }
    }

    const int col = lane & 15;
    const int q   = lane >> 4;
    const int kq  = q * 8;

    // W2^T fragments: coalesced 16B/lane from pre-packed global
    f16x8 bfr[8];
    #pragma unroll
    for (int f = 0; f < 8; ++f)
        bfr[f] = *(const f16x8*)((const char*)w2f + f * 1024 + lane * 16);

    const int n0 = g * 8 + w;               // always < 100 (g<=12 -> n0<=99)
    const int n1 = n0 + 4;
    const bool have1 = (n1 < N_);           // wave-uniform
    const int n1c = have1 ? n1 : n0;
    const int row0 = bt * N_ + n0;
    const int row1 = bt * N_ + n1c;

    const __half* vp0 = v_h + (size_t)row0 * 64;
    const __half* vp1 = v_h + (size_t)row1 * 64;
    const uint4 vv00 = *(const uint4*)(vp0 + kq);
    const uint4 vv01 = *(const uint4*)(vp0 + 32 + kq);
    const uint4 vv10 = *(const uint4*)(vp1 + kq);
    const uint4 vv11 = *(const uint4*)(vp1 + 32 + kq);
    float bb[4];
    #pragma unroll
    for (int nt = 0; nt < 4; ++nt) bb[nt] = b2[nt * 16 + col];
    const float* rtp0 = rtt + ((size_t)b * N_ + n0) * 112 + q * 4;
    const float* rtp1 = rtt + ((size_t)b * N_ + n1c) * 112 + q * 4;

    __syncthreads();                        // u tile landed

    float agg0[4] = {0.f, 0.f, 0.f, 0.f};
    float agg1[4] = {0.f, 0.f, 0.f, 0.f};
    #pragma unroll
    for (int mf = 0; mf < 7; ++mf) {
        const int i = min(mf * 16 + col, N_ - 1);   // sender-direct, clamped
        const uint4 ud0 = *(const uint4*)&u_lds[i * 72 + kq];
        const uint4 ud1 = *(const uint4*)&u_lds[i * 72 + 32 + kq];
        const float4 rt40 = *(const float4*)(rtp0 + mf * 16);
        const float4 rt41 = *(const float4*)(rtp1 + mf * 16);

        f32x4 acc0[4], acc1[4];
        #pragma unroll
        for (int nt = 0; nt < 4; ++nt) {    // bias-preloaded accumulators
            acc0[nt][0] = bb[nt]; acc0[nt][1] = bb[nt];
            acc0[nt][2] = bb[nt]; acc0[nt][3] = bb[nt];
            acc1[nt][0] = bb[nt]; acc1[nt][1] = bb[nt];
            acc1[nt][2] = bb[nt]; acc1[nt][3] = bb[nt];
        }
        const f16x8 a00 = relu_add8(ud0, vv00);   // shared u, per-recv v
        const f16x8 a10 = relu_add8(ud0, vv10);
        const f16x8 a01 = relu_add8(ud1, vv01);
        const f16x8 a11 = relu_add8(ud1, vv11);

        __builtin_amdgcn_s_setprio(1);
        #pragma unroll
        for (int nt = 0; nt < 4; ++nt)
            acc0[nt] = __builtin_amdgcn_mfma_f32_16x16x32_f16(a00, bfr[nt], acc0[nt], 0, 0, 0);
        #pragma unroll
        for (int nt = 0; nt < 4; ++nt)
            acc1[nt] = __builtin_amdgcn_mfma_f32_16x16x32_f16(a10, bfr[nt], acc1[nt], 0, 0, 0);
        #pragma unroll
        for (int nt = 0; nt < 4; ++nt)
            acc0[nt] = __builtin_amdgcn_mfma_f32_16x16x32_f16(a01, bfr[4 + nt], acc0[nt], 0, 0, 0);
        #pragma unroll
        for (int nt = 0; nt < 4; ++nt)
            acc1[nt] = __builtin_amdgcn_mfma_f32_16x16x32_f16(a11, bfr[4 + nt], acc1[nt], 0, 0, 0);
        __builtin_amdgcn_s_setprio(0);

        #pragma unroll
        for (int nt = 0; nt < 4; ++nt) {    // lean fold: max + fma
            agg0[nt] = fmaf(fmaxf(acc0[nt][0], 0.f), rt40.x, agg0[nt]);
            agg0[nt] = fmaf(fmaxf(acc0[nt][1], 0.f), rt40.y, agg0[nt]);
            agg0[nt] = fmaf(fmaxf(acc0[nt][2], 0.f), rt40.z, agg0[nt]);
            agg0[nt] = fmaf(fmaxf(acc0[nt][3], 0.f), rt40.w, agg0[nt]);
            agg1[nt] = fmaf(fmaxf(acc1[nt][0], 0.f), rt41.x, agg1[nt]);
            agg1[nt] = fmaf(fmaxf(acc1[nt][1], 0.f), rt41.y, agg1[nt]);
            agg1[nt] = fmaf(fmaxf(acc1[nt][2], 0.f), rt41.z, agg1[nt]);
            agg1[nt] = fmaf(fmaxf(acc1[nt][3], 0.f), rt41.w, agg1[nt]);
        }
    }
    #pragma unroll
    for (int nt = 0; nt < 4; ++nt) {
        float p = agg0[nt];
        p += __shfl_xor(p, 16, 64);
        p += __shfl_xor(p, 32, 64);
        if (lane < 16)
            ain[(size_t)row0 * 96 + nt * 16 + col] = __float2half(p);
    }
    if (have1) {
        #pragma unroll
        for (int nt = 0; nt < 4; ++nt) {
            float p = agg1[nt];
            p += __shfl_xor(p, 16, 64);
            p += __shfl_xor(p, 32, 64);
            if (lane < 16)
                ain[(size_t)row1 * 96 + nt * 16 + col] = __float2half(p);
        }
    }
}

// ==================== kernel B: out-MLP as MFMA GEMMs (R8 proven) ===========
__global__ __launch_bounds__(256)
void nri_out(const __half* __restrict__ ain, const __half* __restrict__ w1f,
             const __half* __restrict__ w2b, const __half* __restrict__ w3f,
             const float* __restrict__ f1b, const float* __restrict__ f2b,
             const float* __restrict__ f3b, const float* __restrict__ x,
             float* __restrict__ out)
{
    __shared__ __half p1buf[4][16 * 72];

    const int tid  = threadIdx.x;
    const int lane = tid & 63;
    const int w    = tid >> 6;
    const int row0 = (blockIdx.x * 4 + w) * 16;
    if (row0 >= ROWS) return;               // wave-uniform

    const int col = lane & 15;
    const int q   = lane >> 4;
    const int kq  = q * 8;

    f16x8 w1r[12];
    #pragma unroll
    for (int f = 0; f < 12; ++f)
        w1r[f] = *(const f16x8*)((const char*)w1f + f * 1024 + lane * 16);
    f16x8 w2r[8];
    #pragma unroll
    for (int f = 0; f < 8; ++f)
        w2r[f] = *(const f16x8*)((const char*)w2b + f * 1024 + lane * 16);
    float b1v[4], b2v[4];
    #pragma unroll
    for (int nt = 0; nt < 4; ++nt) { b1v[nt] = f1b[nt * 16 + col]; b2v[nt] = f2b[nt * 16 + col]; }
    const float4 b3v = *(const float4*)f3b;
    float w3v[16];
    {
        const uint4 p0 = *(const uint4*)(w3f + col * 16);
        const uint4 p1 = *(const uint4*)(w3f + col * 16 + 8);
        const unsigned* pp0 = (const unsigned*)&p0;
        const unsigned* pp1 = (const unsigned*)&p1;
        #pragma unroll
        for (int i = 0; i < 4; ++i) {
            w3v[2*i]     = __half2float(__ushort_as_half((unsigned short)(pp0[i] & 0xffff)));
            w3v[2*i + 1] = __half2float(__ushort_as_half((unsigned short)(pp0[i] >> 16)));
            w3v[8 + 2*i]     = __half2float(__ushort_as_half((unsigned short)(pp1[i] & 0xffff)));
            w3v[8 + 2*i + 1] = __half2float(__ushort_as_half((unsigned short)(pp1[i] >> 16)));
        }
    }

    // ---- GEMM1: p1 = relu([agg|x|0] @ W1^T + b1), K=96 ----
    f32x4 acc1[4] = {};
    #pragma unroll
    for (int s = 0; s < 3; ++s) {
        const uint4 ad = *(const uint4*)(ain + (size_t)(row0 + col) * 96 + s * 32 + kq);
        const f16x8 af = __builtin_bit_cast(f16x8, ad);
        #pragma unroll
        for (int nt = 0; nt < 4; ++nt)
            acc1[nt] = __builtin_amdgcn_mfma_f32_16x16x32_f16(af, w1r[s * 4 + nt], acc1[nt], 0, 0, 0);
    }
    #pragma unroll
    for (int nt = 0; nt < 4; ++nt)
        #pragma unroll
        for (int j = 0; j < 4; ++j)
            p1buf[w][(q * 4 + j) * 72 + nt * 16 + col] =
                __float2half(fmaxf(acc1[nt][j] + b1v[nt], 0.f));
    asm volatile("s_waitcnt lgkmcnt(0)" ::: "memory");
    __builtin_amdgcn_wave_barrier();

    // ---- GEMM2: p2 = relu(p1 @ W2^T + b2), K=64 ----
    f32x4 acc2[4] = {};
    #pragma unroll
    for (int s = 0; s < 2; ++s) {
        const uint4 pd = *(const uint4*)&p1buf[w][col * 72 + s * 32 + kq];
        const f16x8 af = __builtin_bit_cast(f16x8, pd);
        #pragma unroll
        for (int nt = 0; nt < 4; ++nt)
            acc2[nt] = __builtin_amdgcn_mfma_f32_16x16x32_f16(af, w2r[s * 4 + nt], acc2[nt], 0, 0, 0);
    }
    float p2v[4][4];
    #pragma unroll
    for (int nt = 0; nt < 4; ++nt)
        #pragma unroll
        for (int j = 0; j < 4; ++j)
            p2v[nt][j] = fmaxf(acc2[nt][j] + b2v[nt], 0.f);

    // ---- p3[d] = sum_g w3[d][g] p2[g]: partial per col, butterfly over cols
    float pr[4][4];                          // [d][j]
    #pragma unroll
    for (int d = 0; d < 4; ++d)
        #pragma unroll
        for (int j = 0; j < 4; ++j) {
            float s = w3v[0 * 4 + d] * p2v[0][j] + w3v[1 * 4 + d] * p2v[1][j]
                    + w3v[2 * 4 + d] * p2v[2][j] + w3v[3 * 4 + d] * p2v[3][j];
            s += __shfl_xor(s, 1, 64);
            s += __shfl_xor(s, 2, 64);
            s += __shfl_xor(s, 4, 64);
            s += __shfl_xor(s, 8, 64);
            pr[d][j] = s;
        }

    if (col == 0) {                          // lanes 0,16,32,48: 4 rows each
        #pragma unroll
        for (int j = 0; j < 4; ++j) {
            const int rg = row0 + q * 4 + j;
            const int n  = rg % N_;
            const int bt = rg / N_;
            const int t  = bt % TP_;
            const int b  = bt / TP_;
            const float4 xv = *(const float4*)(x + (((size_t)b * N_ + n) * T_ + t) * D_);
            float4 o;
            o.x = xv.x + b3v.x + pr[0][j];
            o.y = xv.y + b3v.y + pr[1][j];
            o.z = xv.z + b3v.z + pr[2][j];
            o.w = xv.w + b3v.w + pr[3][j];
            *(float4*)(out + (((size_t)b * N_ + n) * TP_ + t) * D_) = o;
        }
    }
}

extern "C" void kernel_launch(void* const* d_in, const int* in_sizes, int n_in,
                              void* d_out, int out_size, void* d_ws, size_t ws_size,
                              hipStream_t stream) {
    const float* x   = (const float*)d_in[0];
    const float* rel = (const float*)d_in[1];
    // d_in[2]=rel_rec, d_in[3]=rel_send: one-hot -> index arithmetic
    const float* w1  = (const float*)d_in[4] + 1 * H_ * 2 * D_;  // k=1 slice
    const float* b1  = (const float*)d_in[5] + 1 * H_;
    const float* w2  = (const float*)d_in[6] + 1 * H_ * H_;
    const float* b2  = (const float*)d_in[7] + 1 * H_;
    const float* f1w = (const float*)d_in[8];
    const float* f1b = (const float*)d_in[9];
    const float* f2w = (const float*)d_in[10];
    const float* f2b = (const float*)d_in[11];
    const float* f3w = (const float*)d_in[12];
    const float* f3b = (const float*)d_in[13];
    float* out = (float*)d_out;

    unsigned char* ws = (unsigned char*)d_ws;   // needs 5,959,680 B
    __half* ain = (__half*)(ws + WS_AIN);
    __half* v_h = (__half*)(ws + WS_V);
    float*  rtt = (float*)(ws + WS_RTT);
    __half* ubf = (__half*)(ws + WS_UBF);
    __half* w2f = (__half*)(ws + WS_W2F);
    __half* w1f = (__half*)(ws + WS_W1F);
    __half* w2b = (__half*)(ws + WS_W2B);
    __half* w3f = (__half*)(ws + WS_W3F);

    // tasks: 12000 u/v rows + 800 rtt + 29 frag waves = 12829 -> 3208 blocks
    nri_prep<<<dim3(3208), 256, 0, stream>>>(x, rel, w1, b1, w2, f1w, f2w, f3w,
                                             ubf, v_h, rtt, ain,
                                             w2f, w1f, w2b, w3f);
    nri_agg<<<dim3(B_ * TP_ * NG), 256, 0, stream>>>(ubf, v_h, rtt, w2f, b2, ain);
    nri_out<<<dim3((ROWS / 16 + 3) / 4), 256, 0, stream>>>(ain, w1f, w2b, w3f,
                                                           f1b, f2b, f3b, x, out);
}

// Round 13
// 39.585 us; speedup vs baseline: 1.2187x; 1.2187x over previous
//
#include <hip/hip_runtime.h>
#include <hip/hip_fp16.h>

#define B_  8
#define N_  100
#define T_  16
#define TP_ 15     // T-1 output steps (pred_steps == 1)
#define D_  4
#define H_  64
#define E_  9900   // N*(N-1)
#define NG  25     // 4 receivers per block in kernel A
#define ROWS 12000 // B*TP*N

// ---- d_ws layout (bytes) ----
#define WS_AIN 0u          // f16 [12000][96]: [agg(64)|x(4)|zeros(28)]  2,304,000
#define WS_V   2304000u    // f16 [12000][64]  receiver-side pre-act     1,536,000
#define WS_RTT 3840000u    // f32 [8][100][112] receiver-major rel_type    358,400
#define WS_UBF 4198400u    // f16 [120][100][72] sender pre-act (+pad)   1,730,560
#define WS_W2F 5928960u    // f16 8 MFMA frags of W2^T (kernel A)            8,192
#define WS_W1F 5937152u    // f16 12 MFMA frags of W1out^T (kernel B g1)    12,288
#define WS_W2B 5949440u    // f16 8 MFMA frags of W2out^T (kernel B g2)      8,192
#define WS_W3F 5957632u    // f16 [64][16] W3out per-lane pack               2,048
                           // total 5,959,680 B

typedef __attribute__((ext_vector_type(8))) _Float16 f16x8;
typedef __attribute__((ext_vector_type(4))) float f32x4;

__device__ __forceinline__ void gload_lds16(const void* g, void* lds) {
    __builtin_amdgcn_global_load_lds(
        (const __attribute__((address_space(1))) void*)g,
        (__attribute__((address_space(3))) void*)lds, 16, 0, 0);
}

// relu(u+v) on 8 packed f16 -> 4x v_pk_add_f16 + 4x v_pk_max_f16
__device__ __forceinline__ f16x8 relu_add8(uint4 u, uint4 v) {
    const f16x8 a = __builtin_bit_cast(f16x8, u);
    const f16x8 b = __builtin_bit_cast(f16x8, v);
    const f16x8 s = a + b;
    const f16x8 z = (f16x8)(_Float16)0;
    return __builtin_elementwise_max(s, z);
}

// ==================== prep: u/v/x rows, rtt gather, weight frags ============
__global__ __launch_bounds__(256)
void nri_prep(const float* __restrict__ x, const float* __restrict__ rel,
              const float* __restrict__ w1, const float* __restrict__ b1,
              const float* __restrict__ w2, const float* __restrict__ f1w,
              const float* __restrict__ f2w, const float* __restrict__ f3w,
              __half* __restrict__ ubf, __half* __restrict__ v_h,
              float* __restrict__ rtt, __half* __restrict__ ain,
              __half* __restrict__ w2f, __half* __restrict__ w1f,
              __half* __restrict__ w2b, __half* __restrict__ w3f)
{
    const int lane = threadIdx.x & 63;
    const int wid  = blockIdx.x * 4 + (threadIdx.x >> 6);

    if (wid < ROWS) {                       // per (b,t,node) row
        const int nn = wid % N_;
        const int bt = wid / N_;
        const int t  = bt % TP_;
        const int b  = bt / TP_;
        const float4 ws4 = *(const float4*)(w1 + lane * 8);
        const float4 wr4 = *(const float4*)(w1 + lane * 8 + 4);
        const float4 xv  = *(const float4*)(x + (((size_t)b * N_ + nn) * T_ + t) * D_);
        const float u = ws4.x * xv.x + ws4.y * xv.y + ws4.z * xv.z + ws4.w * xv.w;
        const float v = wr4.x * xv.x + wr4.y * xv.y + wr4.z * xv.z + wr4.w * xv.w
                        + b1[lane];
        ubf[(size_t)bt * 7200 + nn * 72 + lane] = __float2half(u);
        v_h[(size_t)wid * 64 + lane] = __float2half(v);
        if (lane == 32) {                   // x (f16) into ain[row][64..67]
            const unsigned short h0 = __half_as_ushort(__float2half(xv.x));
            const unsigned short h1 = __half_as_ushort(__float2half(xv.y));
            const unsigned short h2 = __half_as_ushort(__float2half(xv.z));
            const unsigned short h3 = __half_as_ushort(__float2half(xv.w));
            uint2 p; p.x = (unsigned)h0 | ((unsigned)h1 << 16);
                     p.y = (unsigned)h2 | ((unsigned)h3 << 16);
            *(uint2*)(ain + (size_t)wid * 96 + 64) = p;
        } else if (lane >= 33 && lane < 40) {  // zeros ain[row][68..95]
            uint2 zz; zz.x = 0u; zz.y = 0u;
            *(uint2*)(ain + (size_t)wid * 96 + 68 + (lane - 33) * 4) = zz;
        }
    } else if (wid < ROWS + B_ * N_) {      // rtt row per (b, receiver n)
        const int idx = wid - ROWS;
        const int n = idx % N_;
        const int b = idx / N_;
        float* dst = rtt + (size_t)idx * 112;
        const int ia  = lane + (lane >= n ? 1 : 0);
        const int eda = ia * (N_ - 1) + (n < ia ? n : n - 1);
        dst[lane] = rel[((size_t)b * E_ + eda) * 2 + 1];
        if (lane < 48) {
            const int e2 = 64 + lane;
            float rv = 0.f;
            if (e2 < N_ - 1) {
                const int ib  = e2 + (e2 >= n ? 1 : 0);
                const int edb = ib * (N_ - 1) + (n < ib ? n : n - 1);
                rv = rel[((size_t)b * E_ + edb) * 2 + 1];
            }
            dst[64 + lane] = rv;
        }
    } else {                                // weight-fragment packing waves
        const int fid = wid - (ROWS + B_ * N_);
        const int g16 = lane & 15, q = lane >> 4;
        unsigned short h[8];
        if (fid < 8) {                      // W2^T frags (kernel A)
            const int s = fid >> 2, nt = fid & 3;
            const int g = nt * 16 + g16;
            #pragma unroll
            for (int j = 0; j < 8; ++j)
                h[j] = __half_as_ushort(__float2half(
                    w2[(size_t)g * 64 + s * 32 + q * 8 + j]));
            uint4 pv; pv.x = h[0] | ((unsigned)h[1] << 16); pv.y = h[2] | ((unsigned)h[3] << 16);
                      pv.z = h[4] | ((unsigned)h[5] << 16); pv.w = h[6] | ((unsigned)h[7] << 16);
            *(uint4*)(w2f + fid * 512 + lane * 8) = pv;
        } else if (fid < 20) {              // W1out^T frags, K=96 padded
            const int f = fid - 8;
            const int s = f >> 2, nt = f & 3;
            const int g = nt * 16 + g16;
            #pragma unroll
            for (int j = 0; j < 8; ++j) {
                const int k = s * 32 + q * 8 + j;
                float v = 0.f;
                if (k < 64)       v = f1w[(size_t)g * 68 + 4 + k];
                else if (k < 68)  v = f1w[(size_t)g * 68 + (k - 64)];
                h[j] = __half_as_ushort(__float2half(v));
            }
            uint4 pv; pv.x = h[0] | ((unsigned)h[1] << 16); pv.y = h[2] | ((unsigned)h[3] << 16);
                      pv.z = h[4] | ((unsigned)h[5] << 16); pv.w = h[6] | ((unsigned)h[7] << 16);
            *(uint4*)(w1f + f * 512 + lane * 8) = pv;
        } else if (fid < 28) {              // W2out^T frags
            const int f = fid - 20;
            const int s = f >> 2, nt = f & 3;
            const int g = nt * 16 + g16;
            #pragma unroll
            for (int j = 0; j < 8; ++j)
                h[j] = __half_as_ushort(__float2half(
                    f2w[(size_t)g * 64 + s * 32 + q * 8 + j]));
            uint4 pv; pv.x = h[0] | ((unsigned)h[1] << 16); pv.y = h[2] | ((unsigned)h[3] << 16);
                      pv.z = h[4] | ((unsigned)h[5] << 16); pv.w = h[6] | ((unsigned)h[7] << 16);
            *(uint4*)(w2b + f * 512 + lane * 8) = pv;
        } else if (fid == 28) {             // W3 per-lane pack [col][nt*4+d]
            unsigned short hh[16];
            #pragma unroll
            for (int nt = 0; nt < 4; ++nt)
                #pragma unroll
                for (int d = 0; d < 4; ++d)
                    hh[nt * 4 + d] = __half_as_ushort(__float2half(
                        f3w[d * 64 + nt * 16 + g16]));
            uint4 p0, p1;
            p0.x = hh[0] | ((unsigned)hh[1] << 16);  p0.y = hh[2] | ((unsigned)hh[3] << 16);
            p0.z = hh[4] | ((unsigned)hh[5] << 16);  p0.w = hh[6] | ((unsigned)hh[7] << 16);
            p1.x = hh[8] | ((unsigned)hh[9] << 16);  p1.y = hh[10] | ((unsigned)hh[11] << 16);
            p1.z = hh[12] | ((unsigned)hh[13] << 16); p1.w = hh[14] | ((unsigned)hh[15] << 16);
            *(uint4*)(w3f + lane * 16) = p0;
            *(uint4*)(w3f + lane * 16 + 8) = p1;
        }
    }
}

// ==================== kernel A: message MLP + aggregation ===================
// 3000 blocks x 4 waves; one receiver per wave (R8 proven structure).
// NEW: XCD-affinity swizzle — 120 bt-tiles split 15-per-XCD so all 25 blocks
// sharing a ubf tile land on one XCD's L2 (bid = bijective (c, bt-class, g)).
// NEW: s_setprio(1) around the MFMA cluster (T5, independent-wave regime).
__global__ __launch_bounds__(256)
void nri_agg(const __half* __restrict__ ubf, const __half* __restrict__ v_h,
             const float* __restrict__ rtt, const __half* __restrict__ w2f,
             const float* __restrict__ b2, __half* __restrict__ ain)
{
    __shared__ __half u_lds[7680];          // 15,360 B (100 rows x 72 + pad)

    const int tid  = threadIdx.x;
    const int lane = tid & 63;
    const int w    = tid >> 6;
    const int bid  = blockIdx.x;
    // XCD swizzle: c = XCD class (assuming round-robin blockIdx%8 -> XCD)
    const int c   = bid & 7;
    const int idx = bid >> 3;               // 0..374
    const int btc = idx / NG;               // 0..14
    const int g   = idx - btc * NG;         // 0..24
    const int bt  = btc * 8 + c;            // 0..119, bijective
    const int b   = bt / TP_;

    // u-tile DMA: 15 x 1KB chunks
    {
        const char* gsrc = (const char*)(ubf + (size_t)bt * 7200);
        char* ldst = (char*)u_lds;
        #pragma unroll
        for (int j = 0; j < 4; ++j) {
            const int cch = w + 4 * j;      // wave-uniform
            if (cch < 15)
                gload_lds16(gsrc + cch * 1024 + lane * 16, ldst + cch * 1024);
        }
    }

    const int col = lane & 15;
    const int q   = lane >> 4;
    const int kq  = q * 8;

    // W2^T fragments: coalesced 16B/lane from pre-packed global
    f16x8 bfr[8];
    #pragma unroll
    for (int f = 0; f < 8; ++f)
        bfr[f] = *(const f16x8*)((const char*)w2f + f * 1024 + lane * 16);

    const int n   = g * 4 + w;              // this wave's receiver (<100)
    const int row = bt * N_ + n;
    const __half* vp = v_h + (size_t)row * 64;
    const uint4 vv0 = *(const uint4*)(vp + kq);
    const uint4 vv1 = *(const uint4*)(vp + 32 + kq);
    float bb[4];
    #pragma unroll
    for (int nt = 0; nt < 4; ++nt) bb[nt] = b2[nt * 16 + col];
    const float* rtp = rtt + ((size_t)b * N_ + n) * 112 + q * 4;

    __syncthreads();                        // u tile landed

    float aggl[4] = {0.f, 0.f, 0.f, 0.f};
    #pragma unroll
    for (int mf = 0; mf < 7; ++mf) {
        const int e = mf * 16 + col;
        int i = e + (e >= n ? 1 : 0);
        if (i > N_ - 1) i = N_ - 1;         // pad rows masked by rt=0
        const float4 rt4 = *(const float4*)(rtp + mf * 16);
        f32x4 acc[4];
        #pragma unroll
        for (int nt = 0; nt < 4; ++nt) {    // bias-preloaded accumulator
            acc[nt][0] = bb[nt]; acc[nt][1] = bb[nt];
            acc[nt][2] = bb[nt]; acc[nt][3] = bb[nt];
        }
        const uint4 ud0 = *(const uint4*)&u_lds[i * 72 + kq];
        f16x8 af = relu_add8(ud0, vv0);
        __builtin_amdgcn_s_setprio(1);
        #pragma unroll
        for (int nt = 0; nt < 4; ++nt)
            acc[nt] = __builtin_amdgcn_mfma_f32_16x16x32_f16(af, bfr[nt], acc[nt], 0, 0, 0);
        __builtin_amdgcn_s_setprio(0);
        const uint4 ud1 = *(const uint4*)&u_lds[i * 72 + 32 + kq];
        af = relu_add8(ud1, vv1);
        __builtin_amdgcn_s_setprio(1);
        #pragma unroll
        for (int nt = 0; nt < 4; ++nt)
            acc[nt] = __builtin_amdgcn_mfma_f32_16x16x32_f16(af, bfr[4 + nt], acc[nt], 0, 0, 0);
        __builtin_amdgcn_s_setprio(0);
        #pragma unroll
        for (int nt = 0; nt < 4; ++nt) {    // lean fold: max + fma only
            aggl[nt] = fmaf(fmaxf(acc[nt][0], 0.f), rt4.x, aggl[nt]);
            aggl[nt] = fmaf(fmaxf(acc[nt][1], 0.f), rt4.y, aggl[nt]);
            aggl[nt] = fmaf(fmaxf(acc[nt][2], 0.f), rt4.z, aggl[nt]);
            aggl[nt] = fmaf(fmaxf(acc[nt][3], 0.f), rt4.w, aggl[nt]);
        }
    }
    #pragma unroll
    for (int nt = 0; nt < 4; ++nt) {
        float p = aggl[nt];
        p += __shfl_xor(p, 16, 64);
        p += __shfl_xor(p, 32, 64);
        if (lane < 16)
            ain[(size_t)row * 96 + nt * 16 + col] = __float2half(p);
    }
}

// ==================== kernel B: out-MLP as MFMA GEMMs (R8 proven) ===========
__global__ __launch_bounds__(256)
void nri_out(const __half* __restrict__ ain, const __half* __restrict__ w1f,
             const __half* __restrict__ w2b, const __half* __restrict__ w3f,
             const float* __restrict__ f1b, const float* __restrict__ f2b,
             const float* __restrict__ f3b, const float* __restrict__ x,
             float* __restrict__ out)
{
    __shared__ __half p1buf[4][16 * 72];

    const int tid  = threadIdx.x;
    const int lane = tid & 63;
    const int w    = tid >> 6;
    const int row0 = (blockIdx.x * 4 + w) * 16;
    if (row0 >= ROWS) return;               // wave-uniform

    const int col = lane & 15;
    const int q   = lane >> 4;
    const int kq  = q * 8;

    f16x8 w1r[12];
    #pragma unroll
    for (int f = 0; f < 12; ++f)
        w1r[f] = *(const f16x8*)((const char*)w1f + f * 1024 + lane * 16);
    f16x8 w2r[8];
    #pragma unroll
    for (int f = 0; f < 8; ++f)
        w2r[f] = *(const f16x8*)((const char*)w2b + f * 1024 + lane * 16);
    float b1v[4], b2v[4];
    #pragma unroll
    for (int nt = 0; nt < 4; ++nt) { b1v[nt] = f1b[nt * 16 + col]; b2v[nt] = f2b[nt * 16 + col]; }
    const float4 b3v = *(const float4*)f3b;
    float w3v[16];
    {
        const uint4 p0 = *(const uint4*)(w3f + col * 16);
        const uint4 p1 = *(const uint4*)(w3f + col * 16 + 8);
        const unsigned* pp0 = (const unsigned*)&p0;
        const unsigned* pp1 = (const unsigned*)&p1;
        #pragma unroll
        for (int i = 0; i < 4; ++i) {
            w3v[2*i]     = __half2float(__ushort_as_half((unsigned short)(pp0[i] & 0xffff)));
            w3v[2*i + 1] = __half2float(__ushort_as_half((unsigned short)(pp0[i] >> 16)));
            w3v[8 + 2*i]     = __half2float(__ushort_as_half((unsigned short)(pp1[i] & 0xffff)));
            w3v[8 + 2*i + 1] = __half2float(__ushort_as_half((unsigned short)(pp1[i] >> 16)));
        }
    }

    // ---- GEMM1: p1 = relu([agg|x|0] @ W1^T + b1), K=96 ----
    f32x4 acc1[4] = {};
    #pragma unroll
    for (int s = 0; s < 3; ++s) {
        const uint4 ad = *(const uint4*)(ain + (size_t)(row0 + col) * 96 + s * 32 + kq);
        const f16x8 af = __builtin_bit_cast(f16x8, ad);
        #pragma unroll
        for (int nt = 0; nt < 4; ++nt)
            acc1[nt] = __builtin_amdgcn_mfma_f32_16x16x32_f16(af, w1r[s * 4 + nt], acc1[nt], 0, 0, 0);
    }
    #pragma unroll
    for (int nt = 0; nt < 4; ++nt)
        #pragma unroll
        for (int j = 0; j < 4; ++j)
            p1buf[w][(q * 4 + j) * 72 + nt * 16 + col] =
                __float2half(fmaxf(acc1[nt][j] + b1v[nt], 0.f));
    asm volatile("s_waitcnt lgkmcnt(0)" ::: "memory");
    __builtin_amdgcn_wave_barrier();

    // ---- GEMM2: p2 = relu(p1 @ W2^T + b2), K=64 ----
    f32x4 acc2[4] = {};
    #pragma unroll
    for (int s = 0; s < 2; ++s) {
        const uint4 pd = *(const uint4*)&p1buf[w][col * 72 + s * 32 + kq];
        const f16x8 af = __builtin_bit_cast(f16x8, pd);
        #pragma unroll
        for (int nt = 0; nt < 4; ++nt)
            acc2[nt] = __builtin_amdgcn_mfma_f32_16x16x32_f16(af, w2r[s * 4 + nt], acc2[nt], 0, 0, 0);
    }
    float p2v[4][4];
    #pragma unroll
    for (int nt = 0; nt < 4; ++nt)
        #pragma unroll
        for (int j = 0; j < 4; ++j)
            p2v[nt][j] = fmaxf(acc2[nt][j] + b2v[nt], 0.f);

    // ---- p3[d] = sum_g w3[d][g] p2[g]: partial per col, butterfly over cols
    float pr[4][4];                          // [d][j]
    #pragma unroll
    for (int d = 0; d < 4; ++d)
        #pragma unroll
        for (int j = 0; j < 4; ++j) {
            float s = w3v[0 * 4 + d] * p2v[0][j] + w3v[1 * 4 + d] * p2v[1][j]
                    + w3v[2 * 4 + d] * p2v[2][j] + w3v[3 * 4 + d] * p2v[3][j];
            s += __shfl_xor(s, 1, 64);
            s += __shfl_xor(s, 2, 64);
            s += __shfl_xor(s, 4, 64);
            s += __shfl_xor(s, 8, 64);
            pr[d][j] = s;
        }

    if (col == 0) {                          // lanes 0,16,32,48: 4 rows each
        #pragma unroll
        for (int j = 0; j < 4; ++j) {
            const int rg = row0 + q * 4 + j;
            const int n  = rg % N_;
            const int bt = rg / N_;
            const int t  = bt % TP_;
            const int b  = bt / TP_;
            const float4 xv = *(const float4*)(x + (((size_t)b * N_ + n) * T_ + t) * D_);
            float4 o;
            o.x = xv.x + b3v.x + pr[0][j];
            o.y = xv.y + b3v.y + pr[1][j];
            o.z = xv.z + b3v.z + pr[2][j];
            o.w = xv.w + b3v.w + pr[3][j];
            *(float4*)(out + (((size_t)b * N_ + n) * TP_ + t) * D_) = o;
        }
    }
}

extern "C" void kernel_launch(void* const* d_in, const int* in_sizes, int n_in,
                              void* d_out, int out_size, void* d_ws, size_t ws_size,
                              hipStream_t stream) {
    const float* x   = (const float*)d_in[0];
    const float* rel = (const float*)d_in[1];
    // d_in[2]=rel_rec, d_in[3]=rel_send: one-hot -> index arithmetic
    const float* w1  = (const float*)d_in[4] + 1 * H_ * 2 * D_;  // k=1 slice
    const float* b1  = (const float*)d_in[5] + 1 * H_;
    const float* w2  = (const float*)d_in[6] + 1 * H_ * H_;
    const float* b2  = (const float*)d_in[7] + 1 * H_;
    const float* f1w = (const float*)d_in[8];
    const float* f1b = (const float*)d_in[9];
    const float* f2w = (const float*)d_in[10];
    const float* f2b = (const float*)d_in[11];
    const float* f3w = (const float*)d_in[12];
    const float* f3b = (const float*)d_in[13];
    float* out = (float*)d_out;

    unsigned char* ws = (unsigned char*)d_ws;   // needs 5,959,680 B
    __half* ain = (__half*)(ws + WS_AIN);
    __half* v_h = (__half*)(ws + WS_V);
    float*  rtt = (float*)(ws + WS_RTT);
    __half* ubf = (__half*)(ws + WS_UBF);
    __half* w2f = (__half*)(ws + WS_W2F);
    __half* w1f = (__half*)(ws + WS_W1F);
    __half* w2b = (__half*)(ws + WS_W2B);
    __half* w3f = (__half*)(ws + WS_W3F);

    // tasks: 12000 u/v rows + 800 rtt + 29 frag waves = 12829 -> 3208 blocks
    nri_prep<<<dim3(3208), 256, 0, stream>>>(x, rel, w1, b1, w2, f1w, f2w, f3w,
                                             ubf, v_h, rtt, ain,
                                             w2f, w1f, w2b, w3f);
    nri_agg<<<dim3(B_ * TP_ * NG), 256, 0, stream>>>(ubf, v_h, rtt, w2f, b2, ain);
    nri_out<<<dim3((ROWS / 16 + 3) / 4), 256, 0, stream>>>(ain, w1f, w2b, w3f,
                                                           f1b, f2b, f3b, x, out);
}

// Round 14
// 39.439 us; speedup vs baseline: 1.2232x; 1.0037x over previous
//
#include <hip/hip_runtime.h>
#include <hip/hip_fp16.h>

#define B_  8
#define N_  100
#define T_  16
#define TP_ 15     // T-1 output steps (pred_steps == 1)
#define D_  4
#define H_  64
#define E_  9900   // N*(N-1)
#define NG  13     // 8 receivers per block (2 rounds of 4), last group partial
#define ROWS 12000 // B*TP*N

// ---- d_ws layout (bytes) ----
#define WS_AIN 0u          // f16 [12000][96]: [agg(64)|x(4)|zeros(28)]  2,304,000
#define WS_V   2304000u    // f16 [12000][64]  receiver-side pre-act     1,536,000
#define WS_RTT 3840000u    // f32 [8][100][112] receiver-major rel_type    358,400
#define WS_UBF 4198400u    // f16 [120][100][72] sender pre-act (+pad)   1,730,560
#define WS_W2F 5928960u    // f16 8 MFMA frags of W2^T (kernel A)            8,192
#define WS_W1F 5937152u    // f16 12 MFMA frags of W1out^T (kernel B g1)    12,288
#define WS_W2B 5949440u    // f16 8 MFMA frags of W2out^T (kernel B g2)      8,192
#define WS_W3F 5957632u    // f16 [64][16] W3out per-lane pack               2,048
                           // total 5,959,680 B

typedef __attribute__((ext_vector_type(8))) _Float16 f16x8;
typedef __attribute__((ext_vector_type(4))) float f32x4;

__device__ __forceinline__ void gload_lds16(const void* g, void* lds) {
    __builtin_amdgcn_global_load_lds(
        (const __attribute__((address_space(1))) void*)g,
        (__attribute__((address_space(3))) void*)lds, 16, 0, 0);
}

// relu(u+v) on 8 packed f16 -> 4x v_pk_add_f16 + 4x v_pk_max_f16
__device__ __forceinline__ f16x8 relu_add8(uint4 u, uint4 v) {
    const f16x8 a = __builtin_bit_cast(f16x8, u);
    const f16x8 b = __builtin_bit_cast(f16x8, v);
    const f16x8 s = a + b;
    const f16x8 z = (f16x8)(_Float16)0;
    return __builtin_elementwise_max(s, z);
}

// ==================== prep: u/v/x rows, rtt gather, weight frags ============
__global__ __launch_bounds__(256)
void nri_prep(const float* __restrict__ x, const float* __restrict__ rel,
              const float* __restrict__ w1, const float* __restrict__ b1,
              const float* __restrict__ w2, const float* __restrict__ f1w,
              const float* __restrict__ f2w, const float* __restrict__ f3w,
              __half* __restrict__ ubf, __half* __restrict__ v_h,
              float* __restrict__ rtt, __half* __restrict__ ain,
              __half* __restrict__ w2f, __half* __restrict__ w1f,
              __half* __restrict__ w2b, __half* __restrict__ w3f)
{
    const int lane = threadIdx.x & 63;
    const int wid  = blockIdx.x * 4 + (threadIdx.x >> 6);

    if (wid < ROWS) {                       // per (b,t,node) row
        const int nn = wid % N_;
        const int bt = wid / N_;
        const int t  = bt % TP_;
        const int b  = bt / TP_;
        const float4 ws4 = *(const float4*)(w1 + lane * 8);
        const float4 wr4 = *(const float4*)(w1 + lane * 8 + 4);
        const float4 xv  = *(const float4*)(x + (((size_t)b * N_ + nn) * T_ + t) * D_);
        const float u = ws4.x * xv.x + ws4.y * xv.y + ws4.z * xv.z + ws4.w * xv.w;
        const float v = wr4.x * xv.x + wr4.y * xv.y + wr4.z * xv.z + wr4.w * xv.w
                        + b1[lane];
        ubf[(size_t)bt * 7200 + nn * 72 + lane] = __float2half(u);
        v_h[(size_t)wid * 64 + lane] = __float2half(v);
        if (lane == 32) {                   // x (f16) into ain[row][64..67]
            const unsigned short h0 = __half_as_ushort(__float2half(xv.x));
            const unsigned short h1 = __half_as_ushort(__float2half(xv.y));
            const unsigned short h2 = __half_as_ushort(__float2half(xv.z));
            const unsigned short h3 = __half_as_ushort(__float2half(xv.w));
            uint2 p; p.x = (unsigned)h0 | ((unsigned)h1 << 16);
                     p.y = (unsigned)h2 | ((unsigned)h3 << 16);
            *(uint2*)(ain + (size_t)wid * 96 + 64) = p;
        } else if (lane >= 33 && lane < 40) {  // zeros ain[row][68..95]
            uint2 zz; zz.x = 0u; zz.y = 0u;
            *(uint2*)(ain + (size_t)wid * 96 + 68 + (lane - 33) * 4) = zz;
        }
    } else if (wid < ROWS + B_ * N_) {      // rtt row per (b, receiver n)
        const int idx = wid - ROWS;
        const int n = idx % N_;
        const int b = idx / N_;
        float* dst = rtt + (size_t)idx * 112;
        const int ia  = lane + (lane >= n ? 1 : 0);
        const int eda = ia * (N_ - 1) + (n < ia ? n : n - 1);
        dst[lane] = rel[((size_t)b * E_ + eda) * 2 + 1];
        if (lane < 48) {
            const int e2 = 64 + lane;
            float rv = 0.f;
            if (e2 < N_ - 1) {
                const int ib  = e2 + (e2 >= n ? 1 : 0);
                const int edb = ib * (N_ - 1) + (n < ib ? n : n - 1);
                rv = rel[((size_t)b * E_ + edb) * 2 + 1];
            }
            dst[64 + lane] = rv;
        }
    } else {                                // weight-fragment packing waves
        const int fid = wid - (ROWS + B_ * N_);
        const int g16 = lane & 15, q = lane >> 4;
        unsigned short h[8];
        if (fid < 8) {                      // W2^T frags (kernel A)
            const int s = fid >> 2, nt = fid & 3;
            const int g = nt * 16 + g16;
            #pragma unroll
            for (int j = 0; j < 8; ++j)
                h[j] = __half_as_ushort(__float2half(
                    w2[(size_t)g * 64 + s * 32 + q * 8 + j]));
            uint4 pv; pv.x = h[0] | ((unsigned)h[1] << 16); pv.y = h[2] | ((unsigned)h[3] << 16);
                      pv.z = h[4] | ((unsigned)h[5] << 16); pv.w = h[6] | ((unsigned)h[7] << 16);
            *(uint4*)(w2f + fid * 512 + lane * 8) = pv;
        } else if (fid < 20) {              // W1out^T frags, K=96 padded
            const int f = fid - 8;
            const int s = f >> 2, nt = f & 3;
            const int g = nt * 16 + g16;
            #pragma unroll
            for (int j = 0; j < 8; ++j) {
                const int k = s * 32 + q * 8 + j;
                float v = 0.f;
                if (k < 64)       v = f1w[(size_t)g * 68 + 4 + k];
                else if (k < 68)  v = f1w[(size_t)g * 68 + (k - 64)];
                h[j] = __half_as_ushort(__float2half(v));
            }
            uint4 pv; pv.x = h[0] | ((unsigned)h[1] << 16); pv.y = h[2] | ((unsigned)h[3] << 16);
                      pv.z = h[4] | ((unsigned)h[5] << 16); pv.w = h[6] | ((unsigned)h[7] << 16);
            *(uint4*)(w1f + f * 512 + lane * 8) = pv;
        } else if (fid < 28) {              // W2out^T frags
            const int f = fid - 20;
            const int s = f >> 2, nt = f & 3;
            const int g = nt * 16 + g16;
            #pragma unroll
            for (int j = 0; j < 8; ++j)
                h[j] = __half_as_ushort(__float2half(
                    f2w[(size_t)g * 64 + s * 32 + q * 8 + j]));
            uint4 pv; pv.x = h[0] | ((unsigned)h[1] << 16); pv.y = h[2] | ((unsigned)h[3] << 16);
                      pv.z = h[4] | ((unsigned)h[5] << 16); pv.w = h[6] | ((unsigned)h[7] << 16);
            *(uint4*)(w2b + f * 512 + lane * 8) = pv;
        } else if (fid == 28) {             // W3 per-lane pack [col][nt*4+d]
            unsigned short hh[16];
            #pragma unroll
            for (int nt = 0; nt < 4; ++nt)
                #pragma unroll
                for (int d = 0; d < 4; ++d)
                    hh[nt * 4 + d] = __half_as_ushort(__float2half(
                        f3w[d * 64 + nt * 16 + g16]));
            uint4 p0, p1;
            p0.x = hh[0] | ((unsigned)hh[1] << 16);  p0.y = hh[2] | ((unsigned)hh[3] << 16);
            p0.z = hh[4] | ((unsigned)hh[5] << 16);  p0.w = hh[6] | ((unsigned)hh[7] << 16);
            p1.x = hh[8] | ((unsigned)hh[9] << 16);  p1.y = hh[10] | ((unsigned)hh[11] << 16);
            p1.z = hh[12] | ((unsigned)hh[13] << 16); p1.w = hh[14] | ((unsigned)hh[15] << 16);
            *(uint4*)(w3f + lane * 16) = p0;
            *(uint4*)(w3f + lane * 16 + 8) = p1;
        }
    }
}

// ==================== kernel A: message MLP + aggregation ===================
// 1560 blocks x 4 waves; 8 receivers per block = 2 rounds of 4 (one/wave).
// Same u tile both rounds (read-only, no second barrier). Prologue (DMA,
// W2 frags, bias) amortized 2x vs R8. Inner loop identical to R8.
__global__ __launch_bounds__(256)
void nri_agg(const __half* __restrict__ ubf, const __half* __restrict__ v_h,
             const float* __restrict__ rtt, const __half* __restrict__ w2f,
             const float* __restrict__ b2, __half* __restrict__ ain)
{
    __shared__ __half u_lds[7680];          // 15,360 B (100 rows x 72 + pad)

    const int tid  = threadIdx.x;
    const int lane = tid & 63;
    const int w    = tid >> 6;
    const int bid  = blockIdx.x;
    const int G  = bid % NG;                // 8-receiver group
    const int bt = bid / NG;                // 0..119
    const int b  = bt / TP_;

    // u-tile DMA: 15 x 1KB chunks
    {
        const char* gsrc = (const char*)(ubf + (size_t)bt * 7200);
        char* ldst = (char*)u_lds;
        #pragma unroll
        for (int j = 0; j < 4; ++j) {
            const int c = w + 4 * j;        // wave-uniform
            if (c < 15)
                gload_lds16(gsrc + c * 1024 + lane * 16, ldst + c * 1024);
        }
    }

    const int col = lane & 15;
    const int q   = lane >> 4;
    const int kq  = q * 8;

    // W2^T fragments: coalesced 16B/lane from pre-packed global
    f16x8 bfr[8];
    #pragma unroll
    for (int f = 0; f < 8; ++f)
        bfr[f] = *(const f16x8*)((const char*)w2f + f * 1024 + lane * 16);
    float bb[4];
    #pragma unroll
    for (int nt = 0; nt < 4; ++nt) bb[nt] = b2[nt * 16 + col];

    __syncthreads();                        // u tile landed

    #pragma unroll
    for (int r = 0; r < 2; ++r) {
        const int n = G * 8 + r * 4 + w;    // this wave's receiver
        if (n >= N_) continue;              // wave-uniform (only G=12, r=1)
        const int row = bt * N_ + n;
        const __half* vp = v_h + (size_t)row * 64;
        const uint4 vv0 = *(const uint4*)(vp + kq);
        const uint4 vv1 = *(const uint4*)(vp + 32 + kq);
        const float* rtp = rtt + ((size_t)b * N_ + n) * 112 + q * 4;

        float aggl[4] = {0.f, 0.f, 0.f, 0.f};
        #pragma unroll
        for (int mf = 0; mf < 7; ++mf) {
            const int e = mf * 16 + col;
            int i = e + (e >= n ? 1 : 0);
            if (i > N_ - 1) i = N_ - 1;     // pad rows masked by rt=0
            const float4 rt4 = *(const float4*)(rtp + mf * 16);
            f32x4 acc[4];
            #pragma unroll
            for (int nt = 0; nt < 4; ++nt) {  // bias-preloaded accumulator
                acc[nt][0] = bb[nt]; acc[nt][1] = bb[nt];
                acc[nt][2] = bb[nt]; acc[nt][3] = bb[nt];
            }
            const uint4 ud0 = *(const uint4*)&u_lds[i * 72 + kq];
            f16x8 af = relu_add8(ud0, vv0);
            #pragma unroll
            for (int nt = 0; nt < 4; ++nt)
                acc[nt] = __builtin_amdgcn_mfma_f32_16x16x32_f16(
                    af, bfr[nt], acc[nt], 0, 0, 0);
            const uint4 ud1 = *(const uint4*)&u_lds[i * 72 + 32 + kq];
            af = relu_add8(ud1, vv1);
            #pragma unroll
            for (int nt = 0; nt < 4; ++nt)
                acc[nt] = __builtin_amdgcn_mfma_f32_16x16x32_f16(
                    af, bfr[4 + nt], acc[nt], 0, 0, 0);
            #pragma unroll
            for (int nt = 0; nt < 4; ++nt) {  // lean fold: max + fma only
                aggl[nt] = fmaf(fmaxf(acc[nt][0], 0.f), rt4.x, aggl[nt]);
                aggl[nt] = fmaf(fmaxf(acc[nt][1], 0.f), rt4.y, aggl[nt]);
                aggl[nt] = fmaf(fmaxf(acc[nt][2], 0.f), rt4.z, aggl[nt]);
                aggl[nt] = fmaf(fmaxf(acc[nt][3], 0.f), rt4.w, aggl[nt]);
            }
        }
        #pragma unroll
        for (int nt = 0; nt < 4; ++nt) {
            float p = aggl[nt];
            p += __shfl_xor(p, 16, 64);
            p += __shfl_xor(p, 32, 64);
            if (lane < 16)
                ain[(size_t)row * 96 + nt * 16 + col] = __float2half(p);
        }
    }
}

// ==================== kernel B: out-MLP as MFMA GEMMs (R8 proven) ===========
__global__ __launch_bounds__(256)
void nri_out(const __half* __restrict__ ain, const __half* __restrict__ w1f,
             const __half* __restrict__ w2b, const __half* __restrict__ w3f,
             const float* __restrict__ f1b, const float* __restrict__ f2b,
             const float* __restrict__ f3b, const float* __restrict__ x,
             float* __restrict__ out)
{
    __shared__ __half p1buf[4][16 * 72];

    const int tid  = threadIdx.x;
    const int lane = tid & 63;
    const int w    = tid >> 6;
    const int row0 = (blockIdx.x * 4 + w) * 16;
    if (row0 >= ROWS) return;               // wave-uniform

    const int col = lane & 15;
    const int q   = lane >> 4;
    const int kq  = q * 8;

    f16x8 w1r[12];
    #pragma unroll
    for (int f = 0; f < 12; ++f)
        w1r[f] = *(const f16x8*)((const char*)w1f + f * 1024 + lane * 16);
    f16x8 w2r[8];
    #pragma unroll
    for (int f = 0; f < 8; ++f)
        w2r[f] = *(const f16x8*)((const char*)w2b + f * 1024 + lane * 16);
    float b1v[4], b2v[4];
    #pragma unroll
    for (int nt = 0; nt < 4; ++nt) { b1v[nt] = f1b[nt * 16 + col]; b2v[nt] = f2b[nt * 16 + col]; }
    const float4 b3v = *(const float4*)f3b;
    float w3v[16];
    {
        const uint4 p0 = *(const uint4*)(w3f + col * 16);
        const uint4 p1 = *(const uint4*)(w3f + col * 16 + 8);
        const unsigned* pp0 = (const unsigned*)&p0;
        const unsigned* pp1 = (const unsigned*)&p1;
        #pragma unroll
        for (int i = 0; i < 4; ++i) {
            w3v[2*i]     = __half2float(__ushort_as_half((unsigned short)(pp0[i] & 0xffff)));
            w3v[2*i + 1] = __half2float(__ushort_as_half((unsigned short)(pp0[i] >> 16)));
            w3v[8 + 2*i]     = __half2float(__ushort_as_half((unsigned short)(pp1[i] & 0xffff)));
            w3v[8 + 2*i + 1] = __half2float(__ushort_as_half((unsigned short)(pp1[i] >> 16)));
        }
    }

    // ---- GEMM1: p1 = relu([agg|x|0] @ W1^T + b1), K=96 ----
    f32x4 acc1[4] = {};
    #pragma unroll
    for (int s = 0; s < 3; ++s) {
        const uint4 ad = *(const uint4*)(ain + (size_t)(row0 + col) * 96 + s * 32 + kq);
        const f16x8 af = __builtin_bit_cast(f16x8, ad);
        #pragma unroll
        for (int nt = 0; nt < 4; ++nt)
            acc1[nt] = __builtin_amdgcn_mfma_f32_16x16x32_f16(af, w1r[s * 4 + nt], acc1[nt], 0, 0, 0);
    }
    #pragma unroll
    for (int nt = 0; nt < 4; ++nt)
        #pragma unroll
        for (int j = 0; j < 4; ++j)
            p1buf[w][(q * 4 + j) * 72 + nt * 16 + col] =
                __float2half(fmaxf(acc1[nt][j] + b1v[nt], 0.f));
    asm volatile("s_waitcnt lgkmcnt(0)" ::: "memory");
    __builtin_amdgcn_wave_barrier();

    // ---- GEMM2: p2 = relu(p1 @ W2^T + b2), K=64 ----
    f32x4 acc2[4] = {};
    #pragma unroll
    for (int s = 0; s < 2; ++s) {
        const uint4 pd = *(const uint4*)&p1buf[w][col * 72 + s * 32 + kq];
        const f16x8 af = __builtin_bit_cast(f16x8, pd);
        #pragma unroll
        for (int nt = 0; nt < 4; ++nt)
            acc2[nt] = __builtin_amdgcn_mfma_f32_16x16x32_f16(af, w2r[s * 4 + nt], acc2[nt], 0, 0, 0);
    }
    float p2v[4][4];
    #pragma unroll
    for (int nt = 0; nt < 4; ++nt)
        #pragma unroll
        for (int j = 0; j < 4; ++j)
            p2v[nt][j] = fmaxf(acc2[nt][j] + b2v[nt], 0.f);

    // ---- p3[d] = sum_g w3[d][g] p2[g]: partial per col, butterfly over cols
    float pr[4][4];                          // [d][j]
    #pragma unroll
    for (int d = 0; d < 4; ++d)
        #pragma unroll
        for (int j = 0; j < 4; ++j) {
            float s = w3v[0 * 4 + d] * p2v[0][j] + w3v[1 * 4 + d] * p2v[1][j]
                    + w3v[2 * 4 + d] * p2v[2][j] + w3v[3 * 4 + d] * p2v[3][j];
            s += __shfl_xor(s, 1, 64);
            s += __shfl_xor(s, 2, 64);
            s += __shfl_xor(s, 4, 64);
            s += __shfl_xor(s, 8, 64);
            pr[d][j] = s;
        }

    if (col == 0) {                          // lanes 0,16,32,48: 4 rows each
        #pragma unroll
        for (int j = 0; j < 4; ++j) {
            const int rg = row0 + q * 4 + j;
            const int n  = rg % N_;
            const int bt = rg / N_;
            const int t  = bt % TP_;
            const int b  = bt / TP_;
            const float4 xv = *(const float4*)(x + (((size_t)b * N_ + n) * T_ + t) * D_);
            float4 o;
            o.x = xv.x + b3v.x + pr[0][j];
            o.y = xv.y + b3v.y + pr[1][j];
            o.z = xv.z + b3v.z + pr[2][j];
            o.w = xv.w + b3v.w + pr[3][j];
            *(float4*)(out + (((size_t)b * N_ + n) * TP_ + t) * D_) = o;
        }
    }
}

extern "C" void kernel_launch(void* const* d_in, const int* in_sizes, int n_in,
                              void* d_out, int out_size, void* d_ws, size_t ws_size,
                              hipStream_t stream) {
    const float* x   = (const float*)d_in[0];
    const float* rel = (const float*)d_in[1];
    // d_in[2]=rel_rec, d_in[3]=rel_send: one-hot -> index arithmetic
    const float* w1  = (const float*)d_in[4] + 1 * H_ * 2 * D_;  // k=1 slice
    const float* b1  = (const float*)d_in[5] + 1 * H_;
    const float* w2  = (const float*)d_in[6] + 1 * H_ * H_;
    const float* b2  = (const float*)d_in[7] + 1 * H_;
    const float* f1w = (const float*)d_in[8];
    const float* f1b = (const float*)d_in[9];
    const float* f2w = (const float*)d_in[10];
    const float* f2b = (const float*)d_in[11];
    const float* f3w = (const float*)d_in[12];
    const float* f3b = (const float*)d_in[13];
    float* out = (float*)d_out;

    unsigned char* ws = (unsigned char*)d_ws;   // needs 5,959,680 B
    __half* ain = (__half*)(ws + WS_AIN);
    __half* v_h = (__half*)(ws + WS_V);
    float*  rtt = (float*)(ws + WS_RTT);
    __half* ubf = (__half*)(ws + WS_UBF);
    __half* w2f = (__half*)(ws + WS_W2F);
    __half* w1f = (__half*)(ws + WS_W1F);
    __half* w2b = (__half*)(ws + WS_W2B);
    __half* w3f = (__half*)(ws + WS_W3F);

    // tasks: 12000 u/v rows + 800 rtt + 29 frag waves = 12829 -> 3208 blocks
    nri_prep<<<dim3(3208), 256, 0, stream>>>(x, rel, w1, b1, w2, f1w, f2w, f3w,
                                             ubf, v_h, rtt, ain,
                                             w2f, w1f, w2b, w3f);
    nri_agg<<<dim3(120 * NG), 256, 0, stream>>>(ubf, v_h, rtt, w2f, b2, ain);
    nri_out<<<dim3((ROWS / 16 + 3) / 4), 256, 0, stream>>>(ain, w1f, w2b, w3f,
                                                           f1b, f2b, f3b, x, out);
}